// Round 4
// baseline (52.814 us; speedup 1.0000x reference)
//
#include <hip/hip_runtime.h>

#define NBLK 2048
#define TPB  256
// 16 lanes per row-group; 4 groups/wave; 4 waves/block -> 32768 groups.
// Each group processes its 2 rows (r, r+32768) with interleaved scans so
// both rows' loads stay in flight and the merge cost amortizes.

typedef float f32x4 __attribute__((ext_vector_type(4)));

__global__ __launch_bounds__(TPB, 4) void dlr_main(const float* __restrict__ x,
                                                   const int* __restrict__ target,
                                                   double* __restrict__ bsum,
                                                   int B, int C) {
    const int tid  = threadIdx.x;
    const int lane = tid & 63;
    const int l16  = lane & 15;
    const int wid  = (blockIdx.x << 2) + (tid >> 6);
    const int group0  = (wid << 2) + (lane >> 4);
    const int ngroups = NBLK * 16;
    const int n4 = C >> 2;
    const float NEG = -__builtin_inff();

    double lsum = 0.0;

    for (int row = group0; row < B; row += 2 * ngroups) {
        const int rA = row;
        const int rB = row + ngroups;
        const bool hasB = (rB < B);
        const float* rpA = x + (size_t)rA * (size_t)C;
        const float* rpB = x + (size_t)(hasB ? rB : rA) * (size_t)C;  // safe dup
        const f32x4* pA = reinterpret_cast<const f32x4*>(rpA);
        const f32x4* pB = reinterpret_cast<const f32x4*>(rpB);
        const int tA = target[rA];
        const int tB = target[hasB ? rB : rA];
        const float xyA = rpA[tA];   // broadcast within group
        const float xyB = rpB[tB];

        float a1 = NEG, a2 = NEG, a3 = NEG;
        float b1 = NEG, b2 = NEG, b3 = NEG;
        int   ia = 0x7fffffff, ibm = 0x7fffffff;

        for (int ib = 0; ib < n4; ib += 32) {
            f32x4 qa[2], qb[2];
            int c0[2];
            #pragma unroll
            for (int u = 0; u < 2; ++u) {
                const int i = ib + l16 + (u << 4);
                c0[u] = i << 2;
                if (i < n4) {
                    qa[u] = __builtin_nontemporal_load(&pA[i]);
                    qb[u] = __builtin_nontemporal_load(&pB[i]);
                } else {
                    qa[u] = (f32x4){NEG, NEG, NEG, NEG};
                    qb[u] = (f32x4){NEG, NEG, NEG, NEG};
                }
            }
            #pragma unroll
            for (int u = 0; u < 2; ++u) {
                #pragma unroll
                for (int j = 0; j < 4; ++j) {
                    {   const float v = qa[u][j];
                        const float n1 = fmaxf(a1, v);
                        const float n2 = __builtin_amdgcn_fmed3f(v, a1, a2);
                        const float n3 = __builtin_amdgcn_fmed3f(v, a2, a3);
                        if (v > a1) ia = c0[u] + j;   // strict >: min index on ties
                        a1 = n1; a2 = n2; a3 = n3;
                    }
                    {   const float v = qb[u][j];
                        const float n1 = fmaxf(b1, v);
                        const float n2 = __builtin_amdgcn_fmed3f(v, b1, b2);
                        const float n3 = __builtin_amdgcn_fmed3f(v, b2, b3);
                        if (v > b1) ibm = c0[u] + j;
                        b1 = n1; b2 = n2; b3 = n3;
                    }
                }
            }
        }
        // generic tail if C % 4 != 0 (no-op for C=1000)
        for (int c = (n4 << 2) + l16; c < C; c += 16) {
            {   const float v = rpA[c];
                const float n1 = fmaxf(a1, v);
                const float n2 = __builtin_amdgcn_fmed3f(v, a1, a2);
                const float n3 = __builtin_amdgcn_fmed3f(v, a2, a3);
                if (v > a1) ia = c;
                a1 = n1; a2 = n2; a3 = n3;
            }
            {   const float v = rpB[c];
                const float n1 = fmaxf(b1, v);
                const float n2 = __builtin_amdgcn_fmed3f(v, b1, b2);
                const float n3 = __builtin_amdgcn_fmed3f(v, b2, b3);
                if (v > b1) ibm = c;
                b1 = n1; b2 = n2; b3 = n3;
            }
        }

        // 4-step butterfly merges within the 16-lane group (both rows)
        #pragma unroll
        for (int off = 1; off < 16; off <<= 1) {
            {   const float s1 = __shfl_xor(a1, off, 64);
                const float s2 = __shfl_xor(a2, off, 64);
                const float s3 = __shfl_xor(a3, off, 64);
                const int   si = __shfl_xor(ia, off, 64);
                const bool bg = (s1 > a1) || (s1 == a1 && si < ia);
                if (bg) ia = si;
                const float t1 = fmaxf(a1, s1);
                const float t2 = __builtin_amdgcn_fmed3f(s1, a1, a2);
                const float t3 = __builtin_amdgcn_fmed3f(s1, a2, a3);
                const float u2 = fmaxf(t2, s2);
                const float u3 = __builtin_amdgcn_fmed3f(s2, t2, t3);
                a1 = t1; a2 = u2; a3 = fmaxf(u3, s3);
            }
            {   const float s1 = __shfl_xor(b1, off, 64);
                const float s2 = __shfl_xor(b2, off, 64);
                const float s3 = __shfl_xor(b3, off, 64);
                const int   si = __shfl_xor(ibm, off, 64);
                const bool bg = (s1 > b1) || (s1 == b1 && si < ibm);
                if (bg) ibm = si;
                const float t1 = fmaxf(b1, s1);
                const float t2 = __builtin_amdgcn_fmed3f(s1, b1, b2);
                const float t3 = __builtin_amdgcn_fmed3f(s1, b2, b3);
                const float u2 = fmaxf(t2, s2);
                const float u3 = __builtin_amdgcn_fmed3f(s2, t2, t3);
                b1 = t1; b2 = u2; b3 = fmaxf(u3, s3);
            }
        }

        {   const float ind = (ia == tA) ? 1.0f : 0.0f;
            const float num = -(xyA - a2 * ind - a1 * (1.0f - ind));
            lsum += (double)(num / (a1 - a3 + 1e-12f));
        }
        if (hasB) {
            const float ind = (ibm == tB) ? 1.0f : 0.0f;
            const float num = -(xyB - b2 * ind - b1 * (1.0f - ind));
            lsum += (double)(num / (b1 - b3 + 1e-12f));
        }
    }

    // block reduction: one leader per 16-lane group -> 16 doubles in LDS
    __shared__ double s[TPB / 16];
    if (l16 == 0) s[tid >> 4] = lsum;
    __syncthreads();
    if (tid == 0) {
        double b = 0.0;
        #pragma unroll
        for (int i = 0; i < TPB / 16; ++i) b += s[i];
        bsum[blockIdx.x] = b;
    }
}

__global__ void dlr_finalize(const double* __restrict__ bsum,
                             float* __restrict__ out, int B, int n) {
    const int tid = threadIdx.x;   // 256 threads
    double sum = 0.0;
    for (int i = tid; i < n; i += 256) sum += bsum[i];
    #pragma unroll
    for (int off = 32; off > 0; off >>= 1)
        sum += __shfl_xor(sum, off, 64);
    __shared__ double w[4];
    if ((tid & 63) == 0) w[tid >> 6] = sum;
    __syncthreads();
    if (tid == 0)
        out[0] = (float)((w[0] + w[1] + w[2] + w[3]) / (double)B);
}

extern "C" void kernel_launch(void* const* d_in, const int* in_sizes, int n_in,
                              void* d_out, int out_size, void* d_ws, size_t ws_size,
                              hipStream_t stream) {
    const float* x   = (const float*)d_in[0];
    const int*   tgt = (const int*)d_in[1];
    const int B = in_sizes[1];
    const int C = in_sizes[0] / B;

    double* bsum = (double*)d_ws;   // NBLK * 8 = 16 KB scratch

    dlr_main<<<NBLK, TPB, 0, stream>>>(x, tgt, bsum, B, C);
    dlr_finalize<<<1, 256, 0, stream>>>(bsum, (float*)d_out, B, NBLK);
}

// Round 5
// 48.405 us; speedup vs baseline: 1.0911x; 1.0911x over previous
//
#include <hip/hip_runtime.h>

#define NBLK 2048
#define TPB  256
// 16 lanes per row-group; 4 groups/wave; 4 waves/block -> 32768 groups.
// Each group processes 2 rows (r, r+32768) with interleaved scans so both
// rows' loads stay in flight; merges amortize over both rows.
// ind = (x[target] == max) replaces argmax-index tracking (exact-duplicate
// max at target is measure-zero; worst-case mean error ~1.5e-5 << threshold).

typedef float f32x4 __attribute__((ext_vector_type(4)));

__global__ __launch_bounds__(TPB, 8) void dlr_main(const float* __restrict__ x,
                                                   const int* __restrict__ target,
                                                   double* __restrict__ bsum,
                                                   int B, int C) {
    const int tid  = threadIdx.x;
    const int lane = tid & 63;
    const int l16  = lane & 15;
    const int wid  = (blockIdx.x << 2) + (tid >> 6);
    const int group0  = (wid << 2) + (lane >> 4);
    const int ngroups = NBLK * 16;
    const int n4 = C >> 2;
    const float NEG = -__builtin_inff();

    double lsum = 0.0;

    for (int row = group0; row < B; row += 2 * ngroups) {
        const int rA = row;
        const int rB = row + ngroups;
        const bool hasB = (rB < B);
        const float* rpA = x + (size_t)rA * (size_t)C;
        const float* rpB = x + (size_t)(hasB ? rB : rA) * (size_t)C;  // safe dup
        const f32x4* pA = reinterpret_cast<const f32x4*>(rpA);
        const f32x4* pB = reinterpret_cast<const f32x4*>(rpB);
        const float xyA = rpA[target[rA]];            // broadcast within group
        const float xyB = rpB[target[hasB ? rB : rA]];

        float a1 = NEG, a2 = NEG, a3 = NEG;
        float b1 = NEG, b2 = NEG, b3 = NEG;

        for (int ib = 0; ib < n4; ib += 32) {
            f32x4 qa[2], qb[2];
            #pragma unroll
            for (int u = 0; u < 2; ++u) {
                const int i = ib + l16 + (u << 4);
                if (i < n4) {
                    qa[u] = pA[i];
                    qb[u] = pB[i];
                } else {
                    qa[u] = (f32x4){NEG, NEG, NEG, NEG};
                    qb[u] = (f32x4){NEG, NEG, NEG, NEG};
                }
            }
            #pragma unroll
            for (int u = 0; u < 2; ++u) {
                #pragma unroll
                for (int j = 0; j < 4; ++j) {
                    {   const float v = qa[u][j];
                        const float n1 = fmaxf(a1, v);
                        const float n2 = __builtin_amdgcn_fmed3f(v, a1, a2);
                        const float n3 = __builtin_amdgcn_fmed3f(v, a2, a3);
                        a1 = n1; a2 = n2; a3 = n3;
                    }
                    {   const float v = qb[u][j];
                        const float n1 = fmaxf(b1, v);
                        const float n2 = __builtin_amdgcn_fmed3f(v, b1, b2);
                        const float n3 = __builtin_amdgcn_fmed3f(v, b2, b3);
                        b1 = n1; b2 = n2; b3 = n3;
                    }
                }
            }
        }
        // generic tail if C % 4 != 0 (no-op for C=1000)
        for (int c = (n4 << 2) + l16; c < C; c += 16) {
            {   const float v = rpA[c];
                const float n1 = fmaxf(a1, v);
                const float n2 = __builtin_amdgcn_fmed3f(v, a1, a2);
                const float n3 = __builtin_amdgcn_fmed3f(v, a2, a3);
                a1 = n1; a2 = n2; a3 = n3;
            }
            {   const float v = rpB[c];
                const float n1 = fmaxf(b1, v);
                const float n2 = __builtin_amdgcn_fmed3f(v, b1, b2);
                const float n3 = __builtin_amdgcn_fmed3f(v, b2, b3);
                b1 = n1; b2 = n2; b3 = n3;
            }
        }

        // 4-step butterfly merges within the 16-lane group (both rows)
        #pragma unroll
        for (int off = 1; off < 16; off <<= 1) {
            {   const float s1 = __shfl_xor(a1, off, 64);
                const float s2 = __shfl_xor(a2, off, 64);
                const float s3 = __shfl_xor(a3, off, 64);
                const float t1 = fmaxf(a1, s1);
                const float t2 = __builtin_amdgcn_fmed3f(s1, a1, a2);
                const float t3 = __builtin_amdgcn_fmed3f(s1, a2, a3);
                const float u2 = fmaxf(t2, s2);
                const float u3 = __builtin_amdgcn_fmed3f(s2, t2, t3);
                a1 = t1; a2 = u2; a3 = fmaxf(u3, s3);
            }
            {   const float s1 = __shfl_xor(b1, off, 64);
                const float s2 = __shfl_xor(b2, off, 64);
                const float s3 = __shfl_xor(b3, off, 64);
                const float t1 = fmaxf(b1, s1);
                const float t2 = __builtin_amdgcn_fmed3f(s1, b1, b2);
                const float t3 = __builtin_amdgcn_fmed3f(s1, b2, b3);
                const float u2 = fmaxf(t2, s2);
                const float u3 = __builtin_amdgcn_fmed3f(s2, t2, t3);
                b1 = t1; b2 = u2; b3 = fmaxf(u3, s3);
            }
        }

        {   const float ind = (xyA == a1) ? 1.0f : 0.0f;
            const float num = -(xyA - a2 * ind - a1 * (1.0f - ind));
            lsum += (double)(num / (a1 - a3 + 1e-12f));
        }
        if (hasB) {
            const float ind = (xyB == b1) ? 1.0f : 0.0f;
            const float num = -(xyB - b2 * ind - b1 * (1.0f - ind));
            lsum += (double)(num / (b1 - b3 + 1e-12f));
        }
    }

    // block reduction: one leader per 16-lane group -> 16 doubles in LDS
    __shared__ double s[TPB / 16];
    if (l16 == 0) s[tid >> 4] = lsum;
    __syncthreads();
    if (tid == 0) {
        double b = 0.0;
        #pragma unroll
        for (int i = 0; i < TPB / 16; ++i) b += s[i];
        bsum[blockIdx.x] = b;
    }
}

__global__ void dlr_finalize(const double* __restrict__ bsum,
                             float* __restrict__ out, int B, int n) {
    const int tid = threadIdx.x;   // 256 threads
    double sum = 0.0;
    for (int i = tid; i < n; i += 256) sum += bsum[i];
    #pragma unroll
    for (int off = 32; off > 0; off >>= 1)
        sum += __shfl_xor(sum, off, 64);
    __shared__ double w[4];
    if ((tid & 63) == 0) w[tid >> 6] = sum;
    __syncthreads();
    if (tid == 0)
        out[0] = (float)((w[0] + w[1] + w[2] + w[3]) / (double)B);
}

extern "C" void kernel_launch(void* const* d_in, const int* in_sizes, int n_in,
                              void* d_out, int out_size, void* d_ws, size_t ws_size,
                              hipStream_t stream) {
    const float* x   = (const float*)d_in[0];
    const int*   tgt = (const int*)d_in[1];
    const int B = in_sizes[1];
    const int C = in_sizes[0] / B;

    double* bsum = (double*)d_ws;   // NBLK * 8 = 16 KB scratch

    dlr_main<<<NBLK, TPB, 0, stream>>>(x, tgt, bsum, B, C);
    dlr_finalize<<<1, 256, 0, stream>>>(bsum, (float*)d_out, B, NBLK);
}